// Round 1
// baseline (460.548 us; speedup 1.0000x reference)
//
#include <hip/hip_runtime.h>
#include <math.h>

#define S_LEN 8192
#define BATCH 32
#define HDIM 256
#define DDIM 256
#define TS 64           // s-rows per block in att kernel
#define LDK 264         // padded LDS row stride (bf16 elems): 528B rows -> 2-way bank aliasing (free)

typedef float f32x4 __attribute__((ext_vector_type(4)));
typedef short s16x8 __attribute__((ext_vector_type(8)));
typedef short s16x4 __attribute__((ext_vector_type(4)));

static __device__ __forceinline__ unsigned short bf16_rne(float f) {
    unsigned u = __float_as_uint(f);
    u += 0x7FFFu + ((u >> 16) & 1u);
    return (unsigned short)(u >> 16);
}
static __device__ __forceinline__ float bf16_f32(unsigned short h) {
    return __uint_as_float(((unsigned)h) << 16);
}
static __device__ __forceinline__ float fast_tanh(float x) {
    // 1 - 2/(exp(2x)+1); monotone, NaN-free, handles +-inf saturation
    float e = __expf(2.0f * x);
    return 1.0f - 2.0f / (e + 1.0f);
}

// ---------------------------------------------------------------------------
// Kernel 0: blocks [0,32): cin[b][h] = x[b]·W_in[h] + b_in[h] + b_ctx[h]
//           blocks [32,64): W_ctx -> bf16 hi/lo, pre-swizzled into MFMA
//           B-fragment order: Wf[((nt*8+ks)*64 + lane)*8 + j] =
//              W_ctx[h = nt*16 + (lane&15)][d = ks*32 + (lane>>4)*8 + j]
// ---------------------------------------------------------------------------
__global__ void prep_kernel(const float* __restrict__ x,
                            const float* __restrict__ W_in,
                            const float* __restrict__ b_in,
                            const float* __restrict__ W_ctx,
                            const float* __restrict__ b_ctx,
                            float* __restrict__ cin,
                            unsigned short* __restrict__ Wf_hi,
                            unsigned short* __restrict__ Wf_lo) {
    __shared__ float xs[DDIM];
    const int bx = blockIdx.x;
    const int t  = threadIdx.x;
    if (bx < BATCH) {
        xs[t] = x[bx * DDIM + t];
        __syncthreads();
        const float* wr = W_in + t * DDIM;   // thread t owns output h = t
        float acc = b_in[t] + b_ctx[t];
        #pragma unroll 8
        for (int d = 0; d < DDIM; ++d) acc += xs[d] * wr[d];
        cin[bx * HDIM + t] = acc;
    } else {
        const int g  = (bx - BATCH) * 256 + t;   // 0..8191 fragment-groups
        const int nt = g >> 9;
        const int ks = (g >> 6) & 7;
        const int l  = g & 63;
        const int h  = nt * 16 + (l & 15);
        const int d0 = ks * 32 + (l >> 4) * 8;
        const float* src = W_ctx + h * DDIM + d0;
        s16x8 vh, vl;
        #pragma unroll
        for (int j = 0; j < 8; ++j) {
            float f = src[j];
            unsigned short hb = bf16_rne(f);
            vh[j] = (short)hb;
            vl[j] = (short)bf16_rne(f - bf16_f32(hb));
        }
        *(s16x8*)(Wf_hi + (size_t)g * 8) = vh;
        *(s16x8*)(Wf_lo + (size_t)g * 8) = vl;
    }
}

// ---------------------------------------------------------------------------
// Kernel 1: per (s-tile, b) block: ctx GEMM via 3-pass split-bf16 MFMA,
// fused tanh/V-dot epilogue -> att[b][s]; also emits mask floats.
// ---------------------------------------------------------------------------
__launch_bounds__(256, 2)
__global__ void att_kernel(const float* __restrict__ context,
                           const int* __restrict__ mask,
                           const float* __restrict__ cin,
                           const float* __restrict__ V,
                           const unsigned short* __restrict__ Wf_hi,
                           const unsigned short* __restrict__ Wf_lo,
                           float* __restrict__ att,
                           float* __restrict__ out_mask) {
    __shared__ unsigned short a_hi[TS * LDK];   // 33792 B
    __shared__ unsigned short a_lo[TS * LDK];   // 33792 B
    __shared__ float cin_s[HDIM];
    __shared__ float v_s[HDIM];
    __shared__ float att_part[4][TS];

    const int sblk = blockIdx.x;     // 0..127
    const int b    = blockIdx.y;     // 0..31
    const int t    = threadIdx.x;
    const int w    = t >> 6;         // wave 0..3
    const int l    = t & 63;
    const int lane16 = l & 15;
    const int q      = l >> 4;

    cin_s[t] = cin[b * HDIM + t];
    v_s[t]   = V[t];

    // ---- stage context tile [TS][DDIM] fp32 -> bf16 hi/lo in LDS ----
    const float* cbase = context + ((size_t)b * S_LEN + (size_t)sblk * TS) * DDIM;
    #pragma unroll
    for (int i = 0; i < 16; ++i) {
        int f   = i * 256 + t;       // float4 index 0..4095
        int row = f >> 6;            // 64 float4 per row
        int c4  = f & 63;
        f32x4 v = *(const f32x4*)(cbase + row * DDIM + c4 * 4);
        s16x4 hi, lo;
        #pragma unroll
        for (int j = 0; j < 4; ++j) {
            unsigned short hb = bf16_rne(v[j]);
            hi[j] = (short)hb;
            lo[j] = (short)bf16_rne(v[j] - bf16_f32(hb));
        }
        *(s16x4*)(a_hi + row * LDK + c4 * 4) = hi;
        *(s16x4*)(a_lo + row * LDK + c4 * 4) = lo;
    }
    __syncthreads();

    // ---- 3-pass split-bf16 MFMA: acc += Ah*Bh + Ah*Bl + Al*Bh ----
    f32x4 acc[4][4];   // [m-tile][n-tile within wave's group]
    #pragma unroll
    for (int mt = 0; mt < 4; ++mt)
        #pragma unroll
        for (int i = 0; i < 4; ++i) acc[mt][i] = (f32x4){0.f, 0.f, 0.f, 0.f};

    const int ntb = w * 4;           // wave's 4 n-tiles: distinct per wave
    for (int ks = 0; ks < 8; ++ks) {
        s16x8 bh[4], bl[4];
        #pragma unroll
        for (int i = 0; i < 4; ++i) {
            size_t off = ((size_t)((ntb + i) * 8 + ks) * 64 + l) * 8;
            bh[i] = *(const s16x8*)(Wf_hi + off);   // coalesced 16B/lane, L2-hot
            bl[i] = *(const s16x8*)(Wf_lo + off);
        }
        s16x8 ah[4], al[4];
        #pragma unroll
        for (int mt = 0; mt < 4; ++mt) {
            int o = (mt * 16 + lane16) * LDK + ks * 32 + q * 8;
            ah[mt] = *(const s16x8*)(a_hi + o);     // ds_read_b128
            al[mt] = *(const s16x8*)(a_lo + o);
        }
        #pragma unroll
        for (int mt = 0; mt < 4; ++mt)
            #pragma unroll
            for (int i = 0; i < 4; ++i) {
                acc[mt][i] = __builtin_amdgcn_mfma_f32_16x16x32_bf16(ah[mt], bh[i], acc[mt][i], 0, 0, 0);
                acc[mt][i] = __builtin_amdgcn_mfma_f32_16x16x32_bf16(ah[mt], bl[i], acc[mt][i], 0, 0, 0);
                acc[mt][i] = __builtin_amdgcn_mfma_f32_16x16x32_bf16(al[mt], bh[i], acc[mt][i], 0, 0, 0);
            }
    }

    // ---- epilogue: tanh(ctx + cin) * V, reduce over h ----
    // C/D layout: col h' = lane&15 (within n-tile), row s' = quad*4 + reg
    float part[4][4] = {};   // [mt][reg]
    #pragma unroll
    for (int i = 0; i < 4; ++i) {
        int h = (ntb + i) * 16 + lane16;
        float c  = cin_s[h];
        float vv = v_s[h];
        #pragma unroll
        for (int mt = 0; mt < 4; ++mt)
            #pragma unroll
            for (int r = 0; r < 4; ++r)
                part[mt][r] += fast_tanh(acc[mt][i][r] + c) * vv;
    }
    // sum the 16 h-columns within each quad (xor 1,2,4,8 stays inside 16 lanes)
    #pragma unroll
    for (int mt = 0; mt < 4; ++mt)
        #pragma unroll
        for (int r = 0; r < 4; ++r) {
            float v = part[mt][r];
            v += __shfl_xor(v, 1);
            v += __shfl_xor(v, 2);
            v += __shfl_xor(v, 4);
            v += __shfl_xor(v, 8);
            part[mt][r] = v;
        }
    if (lane16 == 0) {
        #pragma unroll
        for (int mt = 0; mt < 4; ++mt)
            #pragma unroll
            for (int r = 0; r < 4; ++r)
                att_part[w][mt * 16 + q * 4 + r] = part[mt][r];
    }
    __syncthreads();

    if (t < TS) {
        float a = att_part[0][t] + att_part[1][t] + att_part[2][t] + att_part[3][t];
        a = 10.0f * fast_tanh(a);
        int s  = sblk * TS + t;
        int mk = mask[b * S_LEN + s];
        att[(size_t)b * S_LEN + s] = mk ? a : -INFINITY;
        out_mask[(size_t)b * S_LEN + s] = mk ? 1.0f : 0.0f;
    }
}

// ---------------------------------------------------------------------------
// Kernel 2: per-b argmax (first-index ties, like jnp.argmax) + p = 1/sum(exp)
// out layout: [0,32) indices as float, [32,64) p, [64,...) mask (written above)
// ---------------------------------------------------------------------------
__global__ void reduce_kernel(const float* __restrict__ att,
                              float* __restrict__ out) {
    __shared__ float smax[256];
    __shared__ int   sidx[256];
    const int b = blockIdx.x;
    const int t = threadIdx.x;
    const float* row = att + (size_t)b * S_LEN;

    float best = -INFINITY;
    int   bid  = 0x7fffffff;
    for (int s = t; s < S_LEN; s += 256) {
        float v = row[s];
        if (v > best) { best = v; bid = s; }   // ascending s -> first index within thread
    }
    smax[t] = best; sidx[t] = bid;
    __syncthreads();
    for (int off = 128; off > 0; off >>= 1) {
        if (t < off) {
            float ov = smax[t + off]; int oi = sidx[t + off];
            if (ov > smax[t] || (ov == smax[t] && oi < sidx[t])) { smax[t] = ov; sidx[t] = oi; }
        }
        __syncthreads();
    }
    const float mx = smax[0];
    const int   ix = sidx[0];
    __syncthreads();

    float sum = 0.f;
    for (int s = t; s < S_LEN; s += 256)
        sum += __expf(row[s] - mx);            // masked -inf -> exp -> 0
    smax[t] = sum;
    __syncthreads();
    for (int off = 128; off > 0; off >>= 1) {
        if (t < off) smax[t] += smax[t + off];
        __syncthreads();
    }
    if (t == 0) {
        out[b]         = (float)ix;
        out[BATCH + b] = 1.0f / smax[0];
    }
}

// ---------------------------------------------------------------------------
extern "C" void kernel_launch(void* const* d_in, const int* in_sizes, int n_in,
                              void* d_out, int out_size, void* d_ws, size_t ws_size,
                              hipStream_t stream) {
    const float* x       = (const float*)d_in[0];
    const float* context = (const float*)d_in[1];
    const int*   mask    = (const int*)d_in[2];
    const float* W_in    = (const float*)d_in[3];
    const float* b_in    = (const float*)d_in[4];
    const float* W_ctx   = (const float*)d_in[5];
    const float* b_ctx   = (const float*)d_in[6];
    const float* V       = (const float*)d_in[7];
    float* out = (float*)d_out;

    char* ws = (char*)d_ws;
    float*          cin   = (float*)ws;                                  // 32 KB
    unsigned short* Wf_hi = (unsigned short*)(ws + 32 * 1024);           // 128 KB
    unsigned short* Wf_lo = (unsigned short*)(ws + 160 * 1024);          // 128 KB
    float*          att   = (float*)(ws + 288 * 1024);                   // 1 MB

    float* out_mask = out + 64;

    prep_kernel<<<64, 256, 0, stream>>>(x, W_in, b_in, W_ctx, b_ctx, cin, Wf_hi, Wf_lo);
    dim3 grid(S_LEN / TS, BATCH);
    att_kernel<<<grid, 256, 0, stream>>>(context, mask, cin, V, Wf_hi, Wf_lo, att, out_mask);
    reduce_kernel<<<BATCH, 256, 0, stream>>>(att, out);
}